// Round 1
// 954.312 us; speedup vs baseline: 1.1386x; 1.1386x over previous
//
#include <hip/hip_runtime.h>
#include <hip/hip_bf16.h>
#include <math.h>

typedef short s16x8 __attribute__((ext_vector_type(8)));
typedef float f32x4 __attribute__((ext_vector_type(4)));
typedef unsigned short u16;

#define NB_ 8

__device__ __forceinline__ float bf2f(__hip_bfloat16 v){ return __bfloat162float(v); }
__device__ __forceinline__ __hip_bfloat16 f2bf(float v){ return __float2bfloat16(v); }
__device__ __forceinline__ u16 f2u(float v){ __hip_bfloat16 b = f2bf(v); return *(u16*)&b; }

__device__ __forceinline__ float fsigm(float x){ return 1.0f / (1.0f + __expf(-x)); }
__device__ __forceinline__ float ftanh(float x){ return 1.0f - 2.0f / (__expf(2.0f * x) + 1.0f); }
__device__ __forceinline__ float fgelu(float x){
    return 0.5f * x * (1.0f + ftanh(0.79788456080286536f * (x + 0.044715f * x * x * x)));
}

// async global->LDS DMA, 16B per lane, lds base must be wave-uniform
__device__ __forceinline__ void async16(u16* lds, const u16* g)
{
    __builtin_amdgcn_global_load_lds((const __attribute__((address_space(1))) void*)g,
                                     (__attribute__((address_space(3))) void*)lds,
                                     16, 0, 0);
}

// ---------------------------------------------------------------------------
// Dual-problem GEMM, double-buffered: blockIdx.y < ysplit -> ga, else gb.
// C[M,N] = A[M,K] @ B[K,N]; A bf16 [M,K] (split at ksplit between A0/A1),
// BT bf16 [N,K]. modes: 0 gelu->bf16, 1 tanh->bf16, 2 residual->fp32 inplace,
// 3 bias->fp32. 128x128 tile, BK=32 (32KB LDS -> 4 blocks/CU via
// __launch_bounds__(256,4)); linear staging (64B rows are naturally
// bank-uniform at whole-wave granularity, no swizzle needed).
// Modes 0/1 restage C through LDS for 16B-coalesced stores.
// ---------------------------------------------------------------------------
struct GArg {
    const u16* A0; const u16* A1; int lda; int ksplit;
    const u16* BT; const float* bias; int bias_stride;
    const float* gate; int gate_stride; const float* meansig;
    u16* outb; float* xio; int N; int K; int idx_off; int mode;
};

__global__ __launch_bounds__(256, 4)
void gemm_dual(GArg ga, GArg gb, int ysplit,
               const int* __restrict__ idxbuf, const float* __restrict__ torsion)
{
    // sm[0..1] = A double buffer, sm[2..3] = B double buffer (32KB total).
    // After the K loop the whole 32KB is reused as the 128x128 bf16 C tile.
    __shared__ __align__(16) u16 sm[4][128 * 32];
    const bool second = (int)blockIdx.y >= ysplit;
    const GArg& g = second ? gb : ga;
    const int n0 = (second ? blockIdx.y - ysplit : blockIdx.y) * 128;
    const int m0 = blockIdx.x * 128;
    const int tid = threadIdx.x;
    const int wave = tid >> 6, lane = tid & 63;
    const int wm = (wave >> 1) * 64, wn = (wave & 1) * 64;
    const int lrow = lane & 15, quad = lane >> 4;

    // staging geometry: each wave stages 2 segments of 512 halfwords for A
    // and for B. slot s = wave*1024 + it*512 + lane*8 -> row = s>>5 (32 u16
    // per row), col = s&31. Linear: 4 consecutive lanes cover one 64B row.
    int rS[2], cS[2];
#pragma unroll
    for (int it = 0; it < 2; it++) {
        int s = wave * 1024 + it * 512 + lane * 8;
        rS[it] = s >> 5;
        cS[it] = s & 31;
    }

    f32x4 acc[4][4] = {};
    const int K = g.K, ksplit = g.ksplit, lda = g.lda, N = g.N;
    const u16* BTn = g.BT + (size_t)n0 * K;
    const int niter = K >> 5;

    auto stage = [&](int k0, int buf) {
        const u16* Ab; int kk;
        if (k0 < ksplit) { Ab = g.A0; kk = k0; }
        else             { Ab = g.A1; kk = k0 - ksplit; }
        const u16* Arow = Ab + (size_t)m0 * lda + kk;
        u16* Ad = &sm[buf][wave * 1024];
        u16* Bd = &sm[2 + buf][wave * 1024];
#pragma unroll
        for (int it = 0; it < 2; it++)
            async16(Ad + it * 512, Arow + (size_t)rS[it] * lda + cS[it]);
#pragma unroll
        for (int it = 0; it < 2; it++)
            async16(Bd + it * 512, BTn + (size_t)rS[it] * K + k0 + cS[it]);
    };

    stage(0, 0);
    __syncthreads();                      // vmcnt(0) drain: tile0 resident

    for (int k = 0; k < niter; k++) {
        int cur = k & 1, nxt = cur ^ 1;
        if (k + 1 < niter) stage((k + 1) << 5, nxt);   // overlap with compute
        s16x8 af[4], bfv[4];
#pragma unroll
        for (int i = 0; i < 4; i++)
            af[i] = *(const s16x8*)&sm[cur][(wm + i * 16 + lrow) * 32 + quad * 8];
#pragma unroll
        for (int j = 0; j < 4; j++)
            bfv[j] = *(const s16x8*)&sm[2 + cur][(wn + j * 16 + lrow) * 32 + quad * 8];
#pragma unroll
        for (int i = 0; i < 4; i++)
#pragma unroll
            for (int j = 0; j < 4; j++)
                acc[i][j] = __builtin_amdgcn_mfma_f32_16x16x32_bf16(af[i], bfv[j], acc[i][j], 0, 0, 0);
        __syncthreads();   // drains vmcnt: tile k+1 resident; buf[cur] reusable
    }

    const int idx = (g.idx_off >= 0) ? idxbuf[g.idx_off] : 0;
    const float* bias = g.bias + (size_t)idx * g.bias_stride;
    const float* gate = g.gate ? (g.gate + (size_t)idx * g.gate_stride) : nullptr;
    const float* msrow = g.meansig ? (g.meansig + (size_t)(m0 >> 9) * 512) : nullptr;
    const int mode = g.mode;

    if (mode <= 1) {
        // bf16 activation output: restage through LDS so global stores are
        // 16B coalesced (direct u16 stores produce 32B segments -> ~2x HBM
        // write amplification). Column XOR by writer-quad keeps the b16
        // scatter writes conflict-free (64 lanes cover the full 128B bank
        // space per instruction).
        u16* CT = &sm[0][0];               // 16384 u16 = full 32KB
#pragma unroll
        for (int j = 0; j < 4; j++) {
            const int n_loc = wn + j * 16 + lrow;
            const float bn = bias[n0 + n_loc];
#pragma unroll
            for (int i = 0; i < 4; i++) {
#pragma unroll
                for (int r = 0; r < 4; r++) {
                    const int m_loc = wm + i * 16 + quad * 4 + r;
                    float v = acc[i][j][r] + bn;
                    v = (mode == 0) ? fgelu(v) : ftanh(v);
                    CT[m_loc * 128 + (n_loc ^ (quad << 4))] = f2u(v);
                }
            }
        }
        __syncthreads();
#pragma unroll
        for (int p = 0; p < 8; p++) {
            int ip  = p * 256 + tid;
            int row = ip >> 4;             // 16 threads per 128-u16 row
            int c0  = (ip & 15) * 8;
            s16x8 vv = *(const s16x8*)&CT[row * 128 + (c0 ^ (((row >> 2) & 3) << 4))];
            *(s16x8*)&g.outb[(size_t)(m0 + row) * N + n0 + c0] = vv;
        }
        return;
    }

#pragma unroll
    for (int j = 0; j < 4; j++) {
        const int n = n0 + wn + j * 16 + lrow;
        const float bn = bias[n];
        float ea = 0.f, ec = 0.f;     // mode-2: v' = ea*v + ec
        if (mode == 2) {
            float tg  = fsigm(gate[n]);
            float tor = torsion[n];
            ea = 0.5f * (1.0f + tg * tor);
            ec = 0.5f * (msrow[n] * 0.3f) * tg;
        }
#pragma unroll
        for (int i = 0; i < 4; i++) {
#pragma unroll
            for (int r = 0; r < 4; r++) {
                const int m = m0 + wm + i * 16 + quad * 4 + r;
                const size_t off = (size_t)m * N + n;
                float v = acc[i][j][r] + bn;
                if (mode == 2) g.xio[off] = g.xio[off] + ea * v + ec;
                else           g.xio[off] = v;
            }
        }
    }
}

// LayerNorm, one row (D=512) per 64-thread block; blocks >=8192 do pathway b
__global__ __launch_bounds__(64)
void ln_dual(const float* __restrict__ xc, const float* __restrict__ xb,
             u16* __restrict__ lnc, u16* __restrict__ lnb,
             const float* __restrict__ cg, const float* __restrict__ cb,
             const float* __restrict__ bg, const float* __restrict__ bb,
             const int* __restrict__ idxbuf, int j)
{
    int bid = blockIdx.x, lane = threadIdx.x;
    bool second = bid >= 8192;
    int row = second ? bid - 8192 : bid;
    const float* x = second ? xb : xc;
    u16* out = second ? lnb : lnc;
    const float* gbase = second ? bg : cg;
    const float* bbase = second ? bb : cb;
    int idx = idxbuf[second ? 2 + j : j];

    const float* xr = x + (size_t)row * 512;
    float4 v0 = *(const float4*)(xr + lane * 8);
    float4 v1 = *(const float4*)(xr + lane * 8 + 4);
    float vals[8] = {v0.x, v0.y, v0.z, v0.w, v1.x, v1.y, v1.z, v1.w};
    float s = 0.f, s2 = 0.f;
#pragma unroll
    for (int t = 0; t < 8; t++) { s += vals[t]; s2 += vals[t] * vals[t]; }
#pragma unroll
    for (int o = 32; o; o >>= 1) { s += __shfl_xor(s, o); s2 += __shfl_xor(s2, o); }
    float mu  = s * (1.f / 512.f);
    float var = s2 * (1.f / 512.f) - mu * mu;
    float rs  = rsqrtf(var + 1e-5f);
    const float* gg  = gbase + (size_t)idx * 512;
    const float* bbp = bbase + (size_t)idx * 512;
    int d0 = lane * 8;
    __align__(16) u16 o8[8];
#pragma unroll
    for (int t = 0; t < 8; t++)
        o8[t] = f2u((vals[t] - mu) * rs * gg[d0 + t] + bbp[d0 + t]);
    *(uint4*)(out + (size_t)row * 512 + d0) = *(const uint4*)o8;
}

__global__ void zero_kernel(float* p, int n)
{
    int i = blockIdx.x * blockDim.x + threadIdx.x;
    if (i < n) p[i] = 0.f;
}

// column means over S: blocks 0..127 -> c (16 b x 8 chunks), 128..255 -> b
__global__ __launch_bounds__(512)
void mean_kernel(const float* __restrict__ xc, const float* __restrict__ xb,
                 float* __restrict__ mc, float* __restrict__ mb)
{
    int bid = blockIdx.x;
    int half = bid >> 7;
    const float* x = half ? xb : xc;
    float* m = half ? mb : mc;
    int b = (bid & 127) >> 3, ch = bid & 7;
    int d = threadIdx.x;
    const float* p = x + ((size_t)b * 512 + ch * 64) * 512 + d;
    float s = 0.f;
#pragma unroll 8
    for (int i = 0; i < 64; i++) s += p[(size_t)i * 512];
    atomicAdd(&m[b * 512 + d], s * (1.f / 512.f));
}

// routing: threads 0..63 -> cortical, 64..127 -> brainstem; top-2 of 8 scores
__global__ __launch_bounds__(128)
void route_kernel(const float* __restrict__ mc, const float* __restrict__ mb,
                  const float* __restrict__ wsel_c, const float* __restrict__ bsel_c,
                  const float* __restrict__ wsel_b, const float* __restrict__ bsel_b,
                  int* __restrict__ idx_out)
{
    int g = threadIdx.x >> 6, lane = threadIdx.x & 63;
    const float* mrow = g ? mb : mc;                 // batch 0 row
    const float* ws = g ? wsel_b : wsel_c;
    const float* bs = g ? bsel_b : bsel_c;
    float acc[8] = {0.f, 0.f, 0.f, 0.f, 0.f, 0.f, 0.f, 0.f};
    for (int d = lane; d < 512; d += 64) {
        float mv = mrow[d];
#pragma unroll
        for (int n = 0; n < 8; n++) acc[n] += mv * ws[d * 8 + n];
    }
#pragma unroll
    for (int o = 32; o; o >>= 1)
#pragma unroll
        for (int n = 0; n < 8; n++) acc[n] += __shfl_xor(acc[n], o);
    if (lane == 0) {
        float adj[8];
#pragma unroll
        for (int n = 0; n < 8; n++) {
            float sc = 1.0f / (1.0f + expf(-(acc[n] + bs[n])));
            adj[n] = 0.7f * sc + 0.15f;
        }
        int i0 = 0;
        for (int n = 1; n < 8; n++) if (adj[n] > adj[i0]) i0 = n;
        int i1 = -1;
        for (int n = 0; n < 8; n++) {
            if (n == i0) continue;
            if (i1 < 0 || adj[n] > adj[i1]) i1 = n;
        }
        idx_out[g * 2 + 0] = i0;
        idx_out[g * 2 + 1] = i1;
    }
}

// up to 4 fp32->bf16 transposes in one launch (src[R][C] -> dst[C][R])
struct TArg { const float* src; u16* dst; int R; int C; int idx_off; int nblk; };

__global__ __launch_bounds__(256)
void transpose4(TArg t0, TArg t1, TArg t2, TArg t3, const int* __restrict__ idxbuf)
{
    int bid = blockIdx.x;
    TArg t;
    if (bid < t0.nblk) t = t0;
    else { bid -= t0.nblk;
        if (bid < t1.nblk) t = t1;
        else { bid -= t1.nblk;
            if (bid < t2.nblk) t = t2;
            else { bid -= t2.nblk; t = t3; } } }
    int idx = (t.idx_off >= 0) ? idxbuf[t.idx_off] : 0;
    const float* src = t.src + (size_t)idx * t.R * t.C;
    int tpr = t.C >> 5;
    int tr = bid / tpr, tc = bid % tpr;
    __shared__ u16 tile[32][33];
    int tx = threadIdx.x & 31, ty = threadIdx.x >> 5;  // 32 x 8
#pragma unroll
    for (int r = ty; r < 32; r += 8)
        tile[r][tx] = f2u(src[(size_t)(tr * 32 + r) * t.C + tc * 32 + tx]);
    __syncthreads();
#pragma unroll
    for (int r = ty; r < 32; r += 8)
        t.dst[(size_t)(tc * 32 + r) * t.R + tr * 32 + tx] = tile[tx][r];
}

// f32 -> bf16, two tensors (blockIdx.y picks tensor), 8 elems/thread
__global__ __launch_bounds__(256)
void f2b_kernel(const float* __restrict__ xa, const float* __restrict__ xb,
                u16* __restrict__ oa, u16* __restrict__ ob)
{
    int i = (blockIdx.x * 256 + threadIdx.x) * 8;
    const float* src = blockIdx.y ? xb : xa;
    u16* dst = blockIdx.y ? ob : oa;
    float4 f0 = *(const float4*)(src + i);
    float4 f1 = *(const float4*)(src + i + 4);
    float vv[8] = {f0.x, f0.y, f0.z, f0.w, f1.x, f1.y, f1.z, f1.w};
    __align__(16) u16 o8[8];
#pragma unroll
    for (int t = 0; t < 8; t++) o8[t] = f2u(vv[t]);
    *(uint4*)(dst + i) = *(const uint4*)o8;
}

extern "C" void kernel_launch(void* const* d_in, const int* in_sizes, int n_in,
                              void* d_out, int out_size, void* d_ws, size_t ws_size,
                              hipStream_t stream)
{
    const float* in_c   = (const float*)d_in[0];
    const float* in_b   = (const float*)d_in[1];
    const float* torsion= (const float*)d_in[2];
    const float* wsel_c = (const float*)d_in[3];
    const float* bsel_c = (const float*)d_in[4];
    const float* wsel_b = (const float*)d_in[5];
    const float* bsel_b = (const float*)d_in[6];
    const float* c_ln_g = (const float*)d_in[7];
    const float* c_ln_b = (const float*)d_in[8];
    const float* c_w1   = (const float*)d_in[9];
    const float* c_b1   = (const float*)d_in[10];
    const float* c_w2   = (const float*)d_in[11];
    const float* c_b2   = (const float*)d_in[12];
    const float* c_gate = (const float*)d_in[13];
    const float* b_ln_g = (const float*)d_in[14];
    const float* b_ln_b = (const float*)d_in[15];
    const float* b_w1   = (const float*)d_in[16];
    const float* b_b1   = (const float*)d_in[17];
    const float* b_w2   = (const float*)d_in[18];
    const float* b_b2   = (const float*)d_in[19];
    const float* b_gate = (const float*)d_in[20];
    const float* w_cross= (const float*)d_in[21];
    const float* b_cross= (const float*)d_in[22];

    const size_t SD = (size_t)8192 * 512;  // elements per [B,S,D] tensor

    // fp32 state lives directly in d_out (no final copies)
    float* x_c  = (float*)d_out;
    float* x_b  = x_c + SD;
    float* out_f = x_b + SD;

    char* w = (char*)d_ws;
    u16* lnc   = (u16*)w; w += SD * 2;                 // 8.4 MB
    u16* lnb   = (u16*)w; w += SD * 2;                 // 8.4 MB
    u16* act_c = (u16*)w; w += SD * 2 * 2;             // 16.8 MB (N=1024)
    u16* act_b = (u16*)w; w += SD * 2;                 // 8.4 MB
    u16* cbf   = (u16*)w; w += SD * 2;                 // 8.4 MB
    u16* bbf   = (u16*)w; w += SD * 2;                 // 8.4 MB
    float* mean_c = (float*)w; w += (size_t)16 * 512 * 4;
    float* mean_b = (float*)w; w += (size_t)16 * 512 * 4;
    int*   idxbuf = (int*)w;   w += 256;
    u16* w1t_c = (u16*)w; w += (size_t)1024 * 512 * 2; // [1024][512]
    u16* w2t_c = (u16*)w; w += (size_t)1024 * 512 * 2; // [512][1024]
    u16* w1t_b = (u16*)w; w += (size_t)512 * 512 * 2;  // [512][512]
    u16* w2t_b = (u16*)w; w += (size_t)512 * 512 * 2;
    u16* wxT   = (u16*)w; w += (size_t)1024 * 512 * 2; // [512][1024]

    // inputs -> fp32 working state (in d_out)
    hipMemcpyAsync(x_c, in_c, SD * 4, hipMemcpyDeviceToDevice, stream);
    hipMemcpyAsync(x_b, in_b, SD * 4, hipMemcpyDeviceToDevice, stream);

    // w_cross[3]^T once
    TArg twx = { w_cross + (size_t)3 * 1024 * 512, wxT, 1024, 512, -1, 512 };
    TArg tz  = { nullptr, nullptr, 32, 32, -1, 0 };
    transpose4<<<512, 256, 0, stream>>>(twx, tz, tz, tz, idxbuf);

    for (int l = 0; l < 4; l++) {
        zero_kernel<<<64, 256, 0, stream>>>(mean_c, 16384);  // mean_c+mean_b contiguous
        mean_kernel<<<256, 512, 0, stream>>>(x_c, x_b, mean_c, mean_b);
        route_kernel<<<1, 128, 0, stream>>>(mean_c, mean_b,
            wsel_c + (size_t)l * 512 * 8, bsel_c + (size_t)l * 8,
            wsel_b + (size_t)l * 512 * 8, bsel_b + (size_t)l * 8, idxbuf);

        for (int j = 0; j < 2; j++) {
            // transpose the 4 selected weight matrices
            TArg tc1 = { c_w1 + (size_t)l * NB_ * 512 * 1024, w1t_c, 512, 1024, j, 512 };
            TArg tc2 = { c_w2 + (size_t)l * NB_ * 1024 * 512, w2t_c, 1024, 512, j, 512 };
            TArg tb1 = { b_w1 + (size_t)l * NB_ * 512 * 512,  w1t_b, 512, 512, 2 + j, 256 };
            TArg tb2 = { b_w2 + (size_t)l * NB_ * 512 * 512,  w2t_b, 512, 512, 2 + j, 256 };
            transpose4<<<1536, 256, 0, stream>>>(tc1, tc2, tb1, tb2, idxbuf);

            // LN both pathways
            ln_dual<<<16384, 64, 0, stream>>>(x_c, x_b, lnc, lnb,
                c_ln_g + (size_t)l * NB_ * 512, c_ln_b + (size_t)l * NB_ * 512,
                b_ln_g + (size_t)l * NB_ * 512, b_ln_b + (size_t)l * NB_ * 512,
                idxbuf, j);

            // GEMM1: c (N=1024, gelu) + b (N=512, tanh)
            GArg g1c = { lnc, nullptr, 512, 1 << 30, w1t_c,
                         c_b1 + (size_t)l * NB_ * 1024, 1024,
                         nullptr, 0, nullptr, act_c, nullptr, 1024, 512, j, 0 };
            GArg g1b = { lnb, nullptr, 512, 1 << 30, w1t_b,
                         b_b1 + (size_t)l * NB_ * 512, 512,
                         nullptr, 0, nullptr, act_b, nullptr, 512, 512, 2 + j, 1 };
            gemm_dual<<<dim3(64, 12), 256, 0, stream>>>(g1c, g1b, 8, idxbuf, torsion);

            // GEMM2: c (K=1024) + b (K=512), residual epilogue into x (fp32)
            GArg g2c = { act_c, nullptr, 1024, 1 << 30, w2t_c,
                         c_b2 + (size_t)l * NB_ * 512, 512,
                         c_gate + (size_t)l * NB_ * 512, 512, mean_b,
                         nullptr, x_c, 512, 1024, j, 2 };
            GArg g2b = { act_b, nullptr, 512, 1 << 30, w2t_b,
                         b_b2 + (size_t)l * NB_ * 512, 512,
                         b_gate + (size_t)l * NB_ * 512, 512, mean_c,
                         nullptr, x_b, 512, 512, 2 + j, 2 };
            gemm_dual<<<dim3(64, 8), 256, 0, stream>>>(g2c, g2b, 4, idxbuf, torsion);
        }
    }

    // bf16 copies of final c/b for the fused GEMM's A operand
    f2b_kernel<<<dim3(2048, 2), 256, 0, stream>>>(x_c, x_b, cbf, bbf);
    // fused = concat([c,b]) @ w_cross[3] + b_cross[3]  (fp32 out)
    GArg gf = { cbf, bbf, 512, 512, wxT,
                b_cross + (size_t)3 * 512, 0,
                nullptr, 0, nullptr, nullptr, out_f, 512, 1024, -1, 3 };
    gemm_dual<<<dim3(64, 4), 256, 0, stream>>>(gf, gf, 4, idxbuf, torsion);
}

// Round 2
// 931.592 us; speedup vs baseline: 1.1664x; 1.0244x over previous
//
#include <hip/hip_runtime.h>
#include <hip/hip_bf16.h>
#include <math.h>

typedef short s16x8 __attribute__((ext_vector_type(8)));
typedef float f32x4 __attribute__((ext_vector_type(4)));
typedef unsigned short u16;

#define NB_ 8

__device__ __forceinline__ float bf2f(__hip_bfloat16 v){ return __bfloat162float(v); }
__device__ __forceinline__ __hip_bfloat16 f2bf(float v){ return __float2bfloat16(v); }
__device__ __forceinline__ u16 f2u(float v){ __hip_bfloat16 b = f2bf(v); return *(u16*)&b; }

__device__ __forceinline__ float fsigm(float x){ return 1.0f / (1.0f + __expf(-x)); }
__device__ __forceinline__ float ftanh(float x){ return 1.0f - 2.0f / (__expf(2.0f * x) + 1.0f); }
__device__ __forceinline__ float fgelu(float x){
    return 0.5f * x * (1.0f + ftanh(0.79788456080286536f * (x + 0.044715f * x * x * x)));
}

// async global->LDS DMA, 16B per lane, lds base must be wave-uniform
__device__ __forceinline__ void async16(u16* lds, const u16* g)
{
    __builtin_amdgcn_global_load_lds((const __attribute__((address_space(1))) void*)g,
                                     (__attribute__((address_space(3))) void*)lds,
                                     16, 0, 0);
}

// ---------------------------------------------------------------------------
// Dual-problem GEMM: blockIdx.y < ysplit -> ga, else gb.
// C[M,N] = A[M,K] @ B[K,N]; A bf16 [M,K] (split at ksplit between A0/A1),
// BT bf16 [N,K]. modes: 0 gelu->bf16, 1 tanh->bf16, 2 residual->fp32 inplace,
// 3 bias->fp32. 128x128 tile, BK=32.
// Depth-3 software pipeline (T3+T4): 3 LDS buffers, counted s_waitcnt vmcnt
// (8/4/0) + raw s_barrier -- prefetched tiles stay in flight ACROSS barriers
// (never a full drain in the main loop).
// LDS chunk-XOR swizzle (T2): stored chunk p of row r holds global chunk
// p ^ ((r>>1)&3); fragment read hits all 8 bankquads per 16-lane quad ->
// 2-way max (free). Modes 0/1 restage C through LDS for 16B stores.
// ---------------------------------------------------------------------------
struct GArg {
    const u16* A0; const u16* A1; int lda; int ksplit;
    const u16* BT; const float* bias; int bias_stride;
    const float* gate; int gate_stride; const float* meansig;
    u16* outb; float* xio; int N; int K; int idx_off; int mode;
};

__global__ __launch_bounds__(256, 3)
void gemm_dual(GArg ga, GArg gb, int ysplit,
               const int* __restrict__ idxbuf, const float* __restrict__ torsion)
{
    // sm[0..2] = A triple buffer, sm[3..5] = B triple buffer (48KB).
    // After the K loop sm[0..3] is reused as the 128x128 bf16 C tile.
    __shared__ __align__(16) u16 sm[6][128 * 32];
    const bool second = (int)blockIdx.y >= ysplit;
    const GArg& g = second ? gb : ga;
    const int n0 = (second ? blockIdx.y - ysplit : blockIdx.y) * 128;
    const int m0 = blockIdx.x * 128;
    const int tid = threadIdx.x;
    const int wave = tid >> 6, lane = tid & 63;
    const int wm = (wave >> 1) * 64, wn = (wave & 1) * 64;
    const int lrow = lane & 15, quad = lane >> 4;
    // fragment read column offset (u16): chunk = quad ^ ((r>>1)&3); r>>1&3
    // depends only on lrow bits 1..2 since row blocks are multiples of 16
    const int coff = ((quad ^ ((lrow >> 1) & 3)) << 3);

    // staging geometry: wave stages 2 segments of 512 u16 for A and for B.
    // slot s -> row = s>>5, chunk pos p = (s>>3)&3; fetch global chunk
    // p ^ ((row>>1)&3)  (inverse of the read-side XOR; involution)
    int rS[2], cS[2];
#pragma unroll
    for (int it = 0; it < 2; it++) {
        int s = wave * 1024 + it * 512 + lane * 8;
        rS[it] = s >> 5;
        int p = (s >> 3) & 3;
        cS[it] = ((p ^ ((rS[it] >> 1) & 3)) << 3);
    }

    f32x4 acc[4][4] = {};
    const int K = g.K, ksplit = g.ksplit, lda = g.lda, N = g.N;
    const u16* BTn = g.BT + (size_t)n0 * K;
    const int niter = K >> 5;

    auto stage = [&](int k0, int buf) {
        const u16* Ab; int kk;
        if (k0 < ksplit) { Ab = g.A0; kk = k0; }
        else             { Ab = g.A1; kk = k0 - ksplit; }
        const u16* Arow = Ab + (size_t)m0 * lda + kk;
        u16* Ad = &sm[buf][wave * 1024];
        u16* Bd = &sm[3 + buf][wave * 1024];
#pragma unroll
        for (int it = 0; it < 2; it++)
            async16(Ad + it * 512, Arow + (size_t)rS[it] * lda + cS[it]);
#pragma unroll
        for (int it = 0; it < 2; it++)
            async16(Bd + it * 512, BTn + (size_t)rS[it] * K + k0 + cS[it]);
    };

    // prologue: tiles 0..2 in flight (12 loads/wave outstanding)
    stage(0, 0);
    if (niter > 1) stage(32, 1);
    if (niter > 2) stage(64, 2);

    int cur = 0;
    for (int k = 0; k < niter; k++) {
        // tile k resident once (outstanding - 4*in_flight_stages_ahead) drain
        const int left = niter - 1 - k;
        if (left >= 2)      asm volatile("s_waitcnt vmcnt(8)" ::: "memory");
        else if (left == 1) asm volatile("s_waitcnt vmcnt(4)" ::: "memory");
        else                asm volatile("s_waitcnt vmcnt(0)" ::: "memory");
        __builtin_amdgcn_sched_barrier(0);
        __builtin_amdgcn_s_barrier();
        __builtin_amdgcn_sched_barrier(0);

        const u16* Ac = &sm[cur][0];
        const u16* Bc = &sm[3 + cur][0];
        s16x8 af[4], bfv[4];
#pragma unroll
        for (int i = 0; i < 4; i++)
            af[i] = *(const s16x8*)&Ac[(wm + i * 16 + lrow) * 32 + coff];
#pragma unroll
        for (int j = 0; j < 4; j++)
            bfv[j] = *(const s16x8*)&Bc[(wn + j * 16 + lrow) * 32 + coff];

        // all waves done reading buf[cur] -> safe to restage it
        asm volatile("s_waitcnt lgkmcnt(0)" ::: "memory");
        __builtin_amdgcn_sched_barrier(0);
        __builtin_amdgcn_s_barrier();
        __builtin_amdgcn_sched_barrier(0);

        if (k + 3 < niter) stage((k + 3) << 5, cur);

        __builtin_amdgcn_s_setprio(1);
#pragma unroll
        for (int i = 0; i < 4; i++)
#pragma unroll
            for (int j = 0; j < 4; j++)
                acc[i][j] = __builtin_amdgcn_mfma_f32_16x16x32_bf16(af[i], bfv[j], acc[i][j], 0, 0, 0);
        __builtin_amdgcn_s_setprio(0);
        __builtin_amdgcn_sched_barrier(0);

        cur = (cur == 2) ? 0 : cur + 1;
    }

    const int idx = (g.idx_off >= 0) ? idxbuf[g.idx_off] : 0;
    const float* bias = g.bias + (size_t)idx * g.bias_stride;
    const float* gate = g.gate ? (g.gate + (size_t)idx * g.gate_stride) : nullptr;
    const float* msrow = g.meansig ? (g.meansig + (size_t)(m0 >> 9) * 512) : nullptr;
    const int mode = g.mode;

    if (mode <= 1) {
        // bf16 activation output: restage through LDS so global stores are
        // 16B coalesced. Column XOR by writer-quad keeps the b16 scatter
        // writes conflict-free.
        u16* CT = &sm[0][0];               // 16384 u16 = 32KB (sm[0..3])
#pragma unroll
        for (int j = 0; j < 4; j++) {
            const int n_loc = wn + j * 16 + lrow;
            const float bn = bias[n0 + n_loc];
#pragma unroll
            for (int i = 0; i < 4; i++) {
#pragma unroll
                for (int r = 0; r < 4; r++) {
                    const int m_loc = wm + i * 16 + quad * 4 + r;
                    float v = acc[i][j][r] + bn;
                    v = (mode == 0) ? fgelu(v) : ftanh(v);
                    CT[m_loc * 128 + (n_loc ^ (quad << 4))] = f2u(v);
                }
            }
        }
        __syncthreads();
#pragma unroll
        for (int p = 0; p < 8; p++) {
            int ip  = p * 256 + tid;
            int row = ip >> 4;             // 16 threads per 128-u16 row
            int c0  = (ip & 15) * 8;
            s16x8 vv = *(const s16x8*)&CT[row * 128 + (c0 ^ (((row >> 2) & 3) << 4))];
            *(s16x8*)&g.outb[(size_t)(m0 + row) * N + n0 + c0] = vv;
        }
        return;
    }

#pragma unroll
    for (int j = 0; j < 4; j++) {
        const int n = n0 + wn + j * 16 + lrow;
        const float bn = bias[n];
        float ea = 0.f, ec = 0.f;     // mode-2: v' = ea*v + ec
        if (mode == 2) {
            float tg  = fsigm(gate[n]);
            float tor = torsion[n];
            ea = 0.5f * (1.0f + tg * tor);
            ec = 0.5f * (msrow[n] * 0.3f) * tg;
        }
#pragma unroll
        for (int i = 0; i < 4; i++) {
#pragma unroll
            for (int r = 0; r < 4; r++) {
                const int m = m0 + wm + i * 16 + quad * 4 + r;
                const size_t off = (size_t)m * N + n;
                float v = acc[i][j][r] + bn;
                if (mode == 2) g.xio[off] = g.xio[off] + ea * v + ec;
                else           g.xio[off] = v;
            }
        }
    }
}

// LayerNorm, one row (D=512) per 64-thread block; blocks >=8192 do pathway b
__global__ __launch_bounds__(64)
void ln_dual(const float* __restrict__ xc, const float* __restrict__ xb,
             u16* __restrict__ lnc, u16* __restrict__ lnb,
             const float* __restrict__ cg, const float* __restrict__ cb,
             const float* __restrict__ bg, const float* __restrict__ bb,
             const int* __restrict__ idxbuf, int j)
{
    int bid = blockIdx.x, lane = threadIdx.x;
    bool second = bid >= 8192;
    int row = second ? bid - 8192 : bid;
    const float* x = second ? xb : xc;
    u16* out = second ? lnb : lnc;
    const float* gbase = second ? bg : cg;
    const float* bbase = second ? bb : cb;
    int idx = idxbuf[second ? 2 + j : j];

    const float* xr = x + (size_t)row * 512;
    float4 v0 = *(const float4*)(xr + lane * 8);
    float4 v1 = *(const float4*)(xr + lane * 8 + 4);
    float vals[8] = {v0.x, v0.y, v0.z, v0.w, v1.x, v1.y, v1.z, v1.w};
    float s = 0.f, s2 = 0.f;
#pragma unroll
    for (int t = 0; t < 8; t++) { s += vals[t]; s2 += vals[t] * vals[t]; }
#pragma unroll
    for (int o = 32; o; o >>= 1) { s += __shfl_xor(s, o); s2 += __shfl_xor(s2, o); }
    float mu  = s * (1.f / 512.f);
    float var = s2 * (1.f / 512.f) - mu * mu;
    float rs  = rsqrtf(var + 1e-5f);
    const float* gg  = gbase + (size_t)idx * 512;
    const float* bbp = bbase + (size_t)idx * 512;
    int d0 = lane * 8;
    __align__(16) u16 o8[8];
#pragma unroll
    for (int t = 0; t < 8; t++)
        o8[t] = f2u((vals[t] - mu) * rs * gg[d0 + t] + bbp[d0 + t]);
    *(uint4*)(out + (size_t)row * 512 + d0) = *(const uint4*)o8;
}

__global__ void zero_kernel(float* p, int n)
{
    int i = blockIdx.x * blockDim.x + threadIdx.x;
    if (i < n) p[i] = 0.f;
}

// column means over S: blocks 0..127 -> c (16 b x 8 chunks), 128..255 -> b
__global__ __launch_bounds__(512)
void mean_kernel(const float* __restrict__ xc, const float* __restrict__ xb,
                 float* __restrict__ mc, float* __restrict__ mb)
{
    int bid = blockIdx.x;
    int half = bid >> 7;
    const float* x = half ? xb : xc;
    float* m = half ? mb : mc;
    int b = (bid & 127) >> 3, ch = bid & 7;
    int d = threadIdx.x;
    const float* p = x + ((size_t)b * 512 + ch * 64) * 512 + d;
    float s = 0.f;
#pragma unroll 8
    for (int i = 0; i < 64; i++) s += p[(size_t)i * 512];
    atomicAdd(&m[b * 512 + d], s * (1.f / 512.f));
}

// routing: threads 0..63 -> cortical, 64..127 -> brainstem; top-2 of 8 scores
__global__ __launch_bounds__(128)
void route_kernel(const float* __restrict__ mc, const float* __restrict__ mb,
                  const float* __restrict__ wsel_c, const float* __restrict__ bsel_c,
                  const float* __restrict__ wsel_b, const float* __restrict__ bsel_b,
                  int* __restrict__ idx_out)
{
    int g = threadIdx.x >> 6, lane = threadIdx.x & 63;
    const float* mrow = g ? mb : mc;                 // batch 0 row
    const float* ws = g ? wsel_b : wsel_c;
    const float* bs = g ? bsel_b : bsel_c;
    float acc[8] = {0.f, 0.f, 0.f, 0.f, 0.f, 0.f, 0.f, 0.f};
    for (int d = lane; d < 512; d += 64) {
        float mv = mrow[d];
#pragma unroll
        for (int n = 0; n < 8; n++) acc[n] += mv * ws[d * 8 + n];
    }
#pragma unroll
    for (int o = 32; o; o >>= 1)
#pragma unroll
        for (int n = 0; n < 8; n++) acc[n] += __shfl_xor(acc[n], o);
    if (lane == 0) {
        float adj[8];
#pragma unroll
        for (int n = 0; n < 8; n++) {
            float sc = 1.0f / (1.0f + expf(-(acc[n] + bs[n])));
            adj[n] = 0.7f * sc + 0.15f;
        }
        int i0 = 0;
        for (int n = 1; n < 8; n++) if (adj[n] > adj[i0]) i0 = n;
        int i1 = -1;
        for (int n = 0; n < 8; n++) {
            if (n == i0) continue;
            if (i1 < 0 || adj[n] > adj[i1]) i1 = n;
        }
        idx_out[g * 2 + 0] = i0;
        idx_out[g * 2 + 1] = i1;
    }
}

// up to 4 fp32->bf16 transposes in one launch (src[R][C] -> dst[C][R])
struct TArg { const float* src; u16* dst; int R; int C; int idx_off; int nblk; };

__global__ __launch_bounds__(256)
void transpose4(TArg t0, TArg t1, TArg t2, TArg t3, const int* __restrict__ idxbuf)
{
    int bid = blockIdx.x;
    TArg t;
    if (bid < t0.nblk) t = t0;
    else { bid -= t0.nblk;
        if (bid < t1.nblk) t = t1;
        else { bid -= t1.nblk;
            if (bid < t2.nblk) t = t2;
            else { bid -= t2.nblk; t = t3; } } }
    int idx = (t.idx_off >= 0) ? idxbuf[t.idx_off] : 0;
    const float* src = t.src + (size_t)idx * t.R * t.C;
    int tpr = t.C >> 5;
    int tr = bid / tpr, tc = bid % tpr;
    __shared__ u16 tile[32][33];
    int tx = threadIdx.x & 31, ty = threadIdx.x >> 5;  // 32 x 8
#pragma unroll
    for (int r = ty; r < 32; r += 8)
        tile[r][tx] = f2u(src[(size_t)(tr * 32 + r) * t.C + tc * 32 + tx]);
    __syncthreads();
#pragma unroll
    for (int r = ty; r < 32; r += 8)
        t.dst[(size_t)(tc * 32 + r) * t.R + tr * 32 + tx] = tile[tx][r];
}

// f32 -> bf16, two tensors (blockIdx.y picks tensor), 8 elems/thread
__global__ __launch_bounds__(256)
void f2b_kernel(const float* __restrict__ xa, const float* __restrict__ xb,
                u16* __restrict__ oa, u16* __restrict__ ob)
{
    int i = (blockIdx.x * 256 + threadIdx.x) * 8;
    const float* src = blockIdx.y ? xb : xa;
    u16* dst = blockIdx.y ? ob : oa;
    float4 f0 = *(const float4*)(src + i);
    float4 f1 = *(const float4*)(src + i + 4);
    float vv[8] = {f0.x, f0.y, f0.z, f0.w, f1.x, f1.y, f1.z, f1.w};
    __align__(16) u16 o8[8];
#pragma unroll
    for (int t = 0; t < 8; t++) o8[t] = f2u(vv[t]);
    *(uint4*)(dst + i) = *(const uint4*)o8;
}

extern "C" void kernel_launch(void* const* d_in, const int* in_sizes, int n_in,
                              void* d_out, int out_size, void* d_ws, size_t ws_size,
                              hipStream_t stream)
{
    const float* in_c   = (const float*)d_in[0];
    const float* in_b   = (const float*)d_in[1];
    const float* torsion= (const float*)d_in[2];
    const float* wsel_c = (const float*)d_in[3];
    const float* bsel_c = (const float*)d_in[4];
    const float* wsel_b = (const float*)d_in[5];
    const float* bsel_b = (const float*)d_in[6];
    const float* c_ln_g = (const float*)d_in[7];
    const float* c_ln_b = (const float*)d_in[8];
    const float* c_w1   = (const float*)d_in[9];
    const float* c_b1   = (const float*)d_in[10];
    const float* c_w2   = (const float*)d_in[11];
    const float* c_b2   = (const float*)d_in[12];
    const float* c_gate = (const float*)d_in[13];
    const float* b_ln_g = (const float*)d_in[14];
    const float* b_ln_b = (const float*)d_in[15];
    const float* b_w1   = (const float*)d_in[16];
    const float* b_b1   = (const float*)d_in[17];
    const float* b_w2   = (const float*)d_in[18];
    const float* b_b2   = (const float*)d_in[19];
    const float* b_gate = (const float*)d_in[20];
    const float* w_cross= (const float*)d_in[21];
    const float* b_cross= (const float*)d_in[22];

    const size_t SD = (size_t)8192 * 512;  // elements per [B,S,D] tensor

    // fp32 state lives directly in d_out (no final copies)
    float* x_c  = (float*)d_out;
    float* x_b  = x_c + SD;
    float* out_f = x_b + SD;

    char* w = (char*)d_ws;
    u16* lnc   = (u16*)w; w += SD * 2;                 // 8.4 MB
    u16* lnb   = (u16*)w; w += SD * 2;                 // 8.4 MB
    u16* act_c = (u16*)w; w += SD * 2 * 2;             // 16.8 MB (N=1024)
    u16* act_b = (u16*)w; w += SD * 2;                 // 8.4 MB
    u16* cbf   = (u16*)w; w += SD * 2;                 // 8.4 MB
    u16* bbf   = (u16*)w; w += SD * 2;                 // 8.4 MB
    float* mean_c = (float*)w; w += (size_t)16 * 512 * 4;
    float* mean_b = (float*)w; w += (size_t)16 * 512 * 4;
    int*   idxbuf = (int*)w;   w += 256;
    u16* w1t_c = (u16*)w; w += (size_t)1024 * 512 * 2; // [1024][512]
    u16* w2t_c = (u16*)w; w += (size_t)1024 * 512 * 2; // [512][1024]
    u16* w1t_b = (u16*)w; w += (size_t)512 * 512 * 2;  // [512][512]
    u16* w2t_b = (u16*)w; w += (size_t)512 * 512 * 2;
    u16* wxT   = (u16*)w; w += (size_t)1024 * 512 * 2; // [512][1024]

    // inputs -> fp32 working state (in d_out)
    hipMemcpyAsync(x_c, in_c, SD * 4, hipMemcpyDeviceToDevice, stream);
    hipMemcpyAsync(x_b, in_b, SD * 4, hipMemcpyDeviceToDevice, stream);

    // w_cross[3]^T once
    TArg twx = { w_cross + (size_t)3 * 1024 * 512, wxT, 1024, 512, -1, 512 };
    TArg tz  = { nullptr, nullptr, 32, 32, -1, 0 };
    transpose4<<<512, 256, 0, stream>>>(twx, tz, tz, tz, idxbuf);

    for (int l = 0; l < 4; l++) {
        zero_kernel<<<64, 256, 0, stream>>>(mean_c, 16384);  // mean_c+mean_b contiguous
        mean_kernel<<<256, 512, 0, stream>>>(x_c, x_b, mean_c, mean_b);
        route_kernel<<<1, 128, 0, stream>>>(mean_c, mean_b,
            wsel_c + (size_t)l * 512 * 8, bsel_c + (size_t)l * 8,
            wsel_b + (size_t)l * 512 * 8, bsel_b + (size_t)l * 8, idxbuf);

        for (int j = 0; j < 2; j++) {
            // transpose the 4 selected weight matrices
            TArg tc1 = { c_w1 + (size_t)l * NB_ * 512 * 1024, w1t_c, 512, 1024, j, 512 };
            TArg tc2 = { c_w2 + (size_t)l * NB_ * 1024 * 512, w2t_c, 1024, 512, j, 512 };
            TArg tb1 = { b_w1 + (size_t)l * NB_ * 512 * 512,  w1t_b, 512, 512, 2 + j, 256 };
            TArg tb2 = { b_w2 + (size_t)l * NB_ * 512 * 512,  w2t_b, 512, 512, 2 + j, 256 };
            transpose4<<<1536, 256, 0, stream>>>(tc1, tc2, tb1, tb2, idxbuf);

            // LN both pathways
            ln_dual<<<16384, 64, 0, stream>>>(x_c, x_b, lnc, lnb,
                c_ln_g + (size_t)l * NB_ * 512, c_ln_b + (size_t)l * NB_ * 512,
                b_ln_g + (size_t)l * NB_ * 512, b_ln_b + (size_t)l * NB_ * 512,
                idxbuf, j);

            // GEMM1: c (N=1024, gelu) + b (N=512, tanh)
            GArg g1c = { lnc, nullptr, 512, 1 << 30, w1t_c,
                         c_b1 + (size_t)l * NB_ * 1024, 1024,
                         nullptr, 0, nullptr, act_c, nullptr, 1024, 512, j, 0 };
            GArg g1b = { lnb, nullptr, 512, 1 << 30, w1t_b,
                         b_b1 + (size_t)l * NB_ * 512, 512,
                         nullptr, 0, nullptr, act_b, nullptr, 512, 512, 2 + j, 1 };
            gemm_dual<<<dim3(64, 12), 256, 0, stream>>>(g1c, g1b, 8, idxbuf, torsion);

            // GEMM2: c (K=1024) + b (K=512), residual epilogue into x (fp32)
            GArg g2c = { act_c, nullptr, 1024, 1 << 30, w2t_c,
                         c_b2 + (size_t)l * NB_ * 512, 512,
                         c_gate + (size_t)l * NB_ * 512, 512, mean_b,
                         nullptr, x_c, 512, 1024, j, 2 };
            GArg g2b = { act_b, nullptr, 512, 1 << 30, w2t_b,
                         b_b2 + (size_t)l * NB_ * 512, 512,
                         b_gate + (size_t)l * NB_ * 512, 512, mean_c,
                         nullptr, x_b, 512, 512, 2 + j, 2 };
            gemm_dual<<<dim3(64, 8), 256, 0, stream>>>(g2c, g2b, 4, idxbuf, torsion);
        }
    }

    // bf16 copies of final c/b for the fused GEMM's A operand
    f2b_kernel<<<dim3(2048, 2), 256, 0, stream>>>(x_c, x_b, cbf, bbf);
    // fused = concat([c,b]) @ w_cross[3] + b_cross[3]  (fp32 out)
    GArg gf = { cbf, bbf, 512, 512, wxT,
                b_cross + (size_t)3 * 512, 0,
                nullptr, 0, nullptr, nullptr, out_f, 512, 1024, -1, 3 };
    gemm_dual<<<dim3(64, 4), 256, 0, stream>>>(gf, gf, 4, idxbuf, torsion);
}

// Round 4
// 930.571 us; speedup vs baseline: 1.1677x; 1.0011x over previous
//
#include <hip/hip_runtime.h>
#include <hip/hip_bf16.h>
#include <math.h>

typedef short s16x8 __attribute__((ext_vector_type(8)));
typedef float f32x4 __attribute__((ext_vector_type(4)));
typedef unsigned short u16;

#define NB_ 8

__device__ __forceinline__ float bf2f(__hip_bfloat16 v){ return __bfloat162float(v); }
__device__ __forceinline__ __hip_bfloat16 f2bf(float v){ return __float2bfloat16(v); }
__device__ __forceinline__ u16 f2u(float v){ __hip_bfloat16 b = f2bf(v); return *(u16*)&b; }

__device__ __forceinline__ float fsigm(float x){ return 1.0f / (1.0f + __expf(-x)); }
__device__ __forceinline__ float ftanh(float x){ return 1.0f - 2.0f / (__expf(2.0f * x) + 1.0f); }
__device__ __forceinline__ float fgelu(float x){
    return 0.5f * x * (1.0f + ftanh(0.79788456080286536f * (x + 0.044715f * x * x * x)));
}

// async global->LDS DMA, 16B per lane, lds base must be wave-uniform
__device__ __forceinline__ void async16(u16* lds, const u16* g)
{
    __builtin_amdgcn_global_load_lds((const __attribute__((address_space(1))) void*)g,
                                     (__attribute__((address_space(3))) void*)lds,
                                     16, 0, 0);
}

// ---------------------------------------------------------------------------
// Dual-problem GEMM: blockIdx.y < ysplit -> ga, else gb.
// C[M,N] = A[M,K] @ B[K,N]; A bf16 [M,K] (split at ksplit between A0/A1),
// BT bf16 [N,K]. modes: 0 gelu->bf16, 1 tanh->bf16, 2 residual->fp32 inplace,
// 3 bias->fp32. 128x128 tile, BK=32.
// Depth-2 pipeline over 3 LDS buffers, counted vmcnt(4) (never drained to 0
// in the main loop), ONE barrier per K-step, and no scheduling pins inside
// the body -- the compiler interleaves ds_read/MFMA with fine lgkmcnt.
// Slot discipline: iter k reads slot k%3, stages into (k+2)%3 (distinct from
// k%3 and (k+1)%3; last read at iter k-1, whose reads completed before the
// top-of-k barrier) -> no second barrier needed.
// LDS chunk-XOR swizzle: stored chunk p of row r holds global chunk
// p ^ ((r>>1)&3); fragment reads hit all 8 bankquads per 16-lane quad
// (conflict-free, verified 0 in round 2). Modes 0/1 restage C through LDS
// for 16B-coalesced stores.
// ---------------------------------------------------------------------------
struct GArg {
    const u16* A0; const u16* A1; int lda; int ksplit;
    const u16* BT; const float* bias; int bias_stride;
    const float* gate; int gate_stride; const float* meansig;
    u16* outb; float* xio; int N; int K; int idx_off; int mode;
};

__global__ __launch_bounds__(256, 3)
void gemm_dual(GArg ga, GArg gb, int ysplit,
               const int* __restrict__ idxbuf, const float* __restrict__ torsion)
{
    // sm[0..2] = A triple buffer, sm[3..5] = B triple buffer (48KB).
    // After the K loop sm[0..3] is reused as the 128x128 bf16 C tile.
    __shared__ __align__(16) u16 sm[6][128 * 32];
    const bool second = (int)blockIdx.y >= ysplit;
    const GArg& g = second ? gb : ga;
    const int n0 = (second ? blockIdx.y - ysplit : blockIdx.y) * 128;
    const int m0 = blockIdx.x * 128;
    const int tid = threadIdx.x;
    const int wave = tid >> 6, lane = tid & 63;
    const int wm = (wave >> 1) * 64, wn = (wave & 1) * 64;
    const int lrow = lane & 15, quad = lane >> 4;
    // fragment read column offset (u16): chunk = quad ^ ((r>>1)&3); row
    // blocks are multiples of 16 so (r>>1)&3 reduces to (lrow>>1)&3
    const int coff = ((quad ^ ((lrow >> 1) & 3)) << 3);

    // staging geometry: wave stages 2 segments of 512 u16 for A and for B.
    // slot s -> row = s>>5, chunk pos p = (s>>3)&3; fetch global chunk
    // p ^ ((row>>1)&3)  (inverse of the read-side XOR; involution)
    int rS[2], cS[2];
#pragma unroll
    for (int it = 0; it < 2; it++) {
        int s = wave * 1024 + it * 512 + lane * 8;
        rS[it] = s >> 5;
        int p = (s >> 3) & 3;
        cS[it] = ((p ^ ((rS[it] >> 1) & 3)) << 3);
    }

    f32x4 acc[4][4] = {};
    const int K = g.K, ksplit = g.ksplit, lda = g.lda, N = g.N;
    const u16* BTn = g.BT + (size_t)n0 * K;
    const int niter = K >> 5;

    auto stage = [&](int k0, int buf) {
        const u16* Ab; int kk;
        if (k0 < ksplit) { Ab = g.A0; kk = k0; }
        else             { Ab = g.A1; kk = k0 - ksplit; }
        const u16* Arow = Ab + (size_t)m0 * lda + kk;
        u16* Ad = &sm[buf][wave * 1024];
        u16* Bd = &sm[3 + buf][wave * 1024];
#pragma unroll
        for (int it = 0; it < 2; it++)
            async16(Ad + it * 512, Arow + (size_t)rS[it] * lda + cS[it]);
#pragma unroll
        for (int it = 0; it < 2; it++)
            async16(Bd + it * 512, BTn + (size_t)rS[it] * K + k0 + cS[it]);
    };

    // prologue: tiles 0..1 in flight (8 loads/wave outstanding)
    stage(0, 0);
    if (niter > 1) stage(32, 1);

    int cur = 0;
    for (int k = 0; k < niter; k++) {
        // tile k resident; tile k+1's 4 loads stay in flight across barrier
        __builtin_amdgcn_sched_barrier(0);
        if (k < niter - 1) asm volatile("s_waitcnt vmcnt(4)" ::: "memory");
        else               asm volatile("s_waitcnt vmcnt(0)" ::: "memory");
        __builtin_amdgcn_s_barrier();
        __builtin_amdgcn_sched_barrier(0);

        int nb = cur + 2; if (nb >= 3) nb -= 3;       // (k+2)%3
        if (k + 2 < niter) stage((k + 2) << 5, nb);

        const u16* Ac = &sm[cur][0];
        const u16* Bc = &sm[3 + cur][0];
        s16x8 af[4], bfv[4];
#pragma unroll
        for (int i = 0; i < 4; i++)
            af[i] = *(const s16x8*)&Ac[(wm + i * 16 + lrow) * 32 + coff];
#pragma unroll
        for (int j = 0; j < 4; j++)
            bfv[j] = *(const s16x8*)&Bc[(wn + j * 16 + lrow) * 32 + coff];
#pragma unroll
        for (int i = 0; i < 4; i++)
#pragma unroll
            for (int j = 0; j < 4; j++)
                acc[i][j] = __builtin_amdgcn_mfma_f32_16x16x32_bf16(af[i], bfv[j], acc[i][j], 0, 0, 0);

        cur = (cur == 2) ? 0 : cur + 1;
    }

    const int idx = (g.idx_off >= 0) ? idxbuf[g.idx_off] : 0;
    const float* bias = g.bias + (size_t)idx * g.bias_stride;
    const float* gate = g.gate ? (g.gate + (size_t)idx * g.gate_stride) : nullptr;
    const float* msrow = g.meansig ? (g.meansig + (size_t)(m0 >> 9) * 512) : nullptr;
    const int mode = g.mode;

    if (mode <= 1) {
        // bf16 activation output: restage through LDS so global stores are
        // 16B coalesced. CT overlaps the frag buffers -> barrier first.
        __syncthreads();
        u16* CT = &sm[0][0];               // 16384 u16 = 32KB (sm[0..3])
#pragma unroll
        for (int j = 0; j < 4; j++) {
            const int n_loc = wn + j * 16 + lrow;
            const float bn = bias[n0 + n_loc];
#pragma unroll
            for (int i = 0; i < 4; i++) {
#pragma unroll
                for (int r = 0; r < 4; r++) {
                    const int m_loc = wm + i * 16 + quad * 4 + r;
                    float v = acc[i][j][r] + bn;
                    v = (mode == 0) ? fgelu(v) : ftanh(v);
                    CT[m_loc * 128 + (n_loc ^ (quad << 4))] = f2u(v);
                }
            }
        }
        __syncthreads();
#pragma unroll
        for (int p = 0; p < 8; p++) {
            int ip  = p * 256 + tid;
            int row = ip >> 4;             // 16 threads per 128-u16 row
            int c0  = (ip & 15) * 8;
            s16x8 vv = *(const s16x8*)&CT[row * 128 + (c0 ^ (((row >> 2) & 3) << 4))];
            *(s16x8*)&g.outb[(size_t)(m0 + row) * N + n0 + c0] = vv;
        }
        return;
    }

#pragma unroll
    for (int j = 0; j < 4; j++) {
        const int n = n0 + wn + j * 16 + lrow;
        const float bn = bias[n];
        float ea = 0.f, ec = 0.f;     // mode-2: v' = ea*v + ec
        if (mode == 2) {
            float tg  = fsigm(gate[n]);
            float tor = torsion[n];
            ea = 0.5f * (1.0f + tg * tor);
            ec = 0.5f * (msrow[n] * 0.3f) * tg;
        }
#pragma unroll
        for (int i = 0; i < 4; i++) {
#pragma unroll
            for (int r = 0; r < 4; r++) {
                const int m = m0 + wm + i * 16 + quad * 4 + r;
                const size_t off = (size_t)m * N + n;
                float v = acc[i][j][r] + bn;
                if (mode == 2) g.xio[off] = g.xio[off] + ea * v + ec;
                else           g.xio[off] = v;
            }
        }
    }
}

// LayerNorm, one row (D=512) per 64-thread block; blocks >=8192 do pathway b
__global__ __launch_bounds__(64)
void ln_dual(const float* __restrict__ xc, const float* __restrict__ xb,
             u16* __restrict__ lnc, u16* __restrict__ lnb,
             const float* __restrict__ cg, const float* __restrict__ cb,
             const float* __restrict__ bg, const float* __restrict__ bb,
             const int* __restrict__ idxbuf, int j)
{
    int bid = blockIdx.x, lane = threadIdx.x;
    bool second = bid >= 8192;
    int row = second ? bid - 8192 : bid;
    const float* x = second ? xb : xc;
    u16* out = second ? lnb : lnc;
    const float* gbase = second ? bg : cg;
    const float* bbase = second ? bb : cb;
    int idx = idxbuf[second ? 2 + j : j];

    const float* xr = x + (size_t)row * 512;
    float4 v0 = *(const float4*)(xr + lane * 8);
    float4 v1 = *(const float4*)(xr + lane * 8 + 4);
    float vals[8] = {v0.x, v0.y, v0.z, v0.w, v1.x, v1.y, v1.z, v1.w};
    float s = 0.f, s2 = 0.f;
#pragma unroll
    for (int t = 0; t < 8; t++) { s += vals[t]; s2 += vals[t] * vals[t]; }
#pragma unroll
    for (int o = 32; o; o >>= 1) { s += __shfl_xor(s, o); s2 += __shfl_xor(s2, o); }
    float mu  = s * (1.f / 512.f);
    float var = s2 * (1.f / 512.f) - mu * mu;
    float rs  = rsqrtf(var + 1e-5f);
    const float* gg  = gbase + (size_t)idx * 512;
    const float* bbp = bbase + (size_t)idx * 512;
    int d0 = lane * 8;
    __align__(16) u16 o8[8];
#pragma unroll
    for (int t = 0; t < 8; t++)
        o8[t] = f2u((vals[t] - mu) * rs * gg[d0 + t] + bbp[d0 + t]);
    *(uint4*)(out + (size_t)row * 512 + d0) = *(const uint4*)o8;
}

__global__ void zero_kernel(float* p, int n)
{
    int i = blockIdx.x * blockDim.x + threadIdx.x;
    if (i < n) p[i] = 0.f;
}

// column means over S: blocks 0..127 -> c (16 b x 8 chunks), 128..255 -> b
__global__ __launch_bounds__(512)
void mean_kernel(const float* __restrict__ xc, const float* __restrict__ xb,
                 float* __restrict__ mc, float* __restrict__ mb)
{
    int bid = blockIdx.x;
    int half = bid >> 7;
    const float* x = half ? xb : xc;
    float* m = half ? mb : mc;
    int b = (bid & 127) >> 3, ch = bid & 7;
    int d = threadIdx.x;
    const float* p = x + ((size_t)b * 512 + ch * 64) * 512 + d;
    float s = 0.f;
#pragma unroll 8
    for (int i = 0; i < 64; i++) s += p[(size_t)i * 512];
    atomicAdd(&m[b * 512 + d], s * (1.f / 512.f));
}

// routing: threads 0..63 -> cortical, 64..127 -> brainstem; top-2 of 8 scores
__global__ __launch_bounds__(128)
void route_kernel(const float* __restrict__ mc, const float* __restrict__ mb,
                  const float* __restrict__ wsel_c, const float* __restrict__ bsel_c,
                  const float* __restrict__ wsel_b, const float* __restrict__ bsel_b,
                  int* __restrict__ idx_out)
{
    int g = threadIdx.x >> 6, lane = threadIdx.x & 63;
    const float* mrow = g ? mb : mc;                 // batch 0 row
    const float* ws = g ? wsel_b : wsel_c;
    const float* bs = g ? bsel_b : bsel_c;
    float acc[8] = {0.f, 0.f, 0.f, 0.f, 0.f, 0.f, 0.f, 0.f};
    for (int d = lane; d < 512; d += 64) {
        float mv = mrow[d];
#pragma unroll
        for (int n = 0; n < 8; n++) acc[n] += mv * ws[d * 8 + n];
    }
#pragma unroll
    for (int o = 32; o; o >>= 1)
#pragma unroll
        for (int n = 0; n < 8; n++) acc[n] += __shfl_xor(acc[n], o);
    if (lane == 0) {
        float adj[8];
#pragma unroll
        for (int n = 0; n < 8; n++) {
            float sc = 1.0f / (1.0f + expf(-(acc[n] + bs[n])));
            adj[n] = 0.7f * sc + 0.15f;
        }
        int i0 = 0;
        for (int n = 1; n < 8; n++) if (adj[n] > adj[i0]) i0 = n;
        int i1 = -1;
        for (int n = 0; n < 8; n++) {
            if (n == i0) continue;
            if (i1 < 0 || adj[n] > adj[i1]) i1 = n;
        }
        idx_out[g * 2 + 0] = i0;
        idx_out[g * 2 + 1] = i1;
    }
}

// up to 4 fp32->bf16 transposes in one launch (src[R][C] -> dst[C][R])
struct TArg { const float* src; u16* dst; int R; int C; int idx_off; int nblk; };

__global__ __launch_bounds__(256)
void transpose4(TArg t0, TArg t1, TArg t2, TArg t3, const int* __restrict__ idxbuf)
{
    int bid = blockIdx.x;
    TArg t;
    if (bid < t0.nblk) t = t0;
    else { bid -= t0.nblk;
        if (bid < t1.nblk) t = t1;
        else { bid -= t1.nblk;
            if (bid < t2.nblk) t = t2;
            else { bid -= t2.nblk; t = t3; } } }
    int idx = (t.idx_off >= 0) ? idxbuf[t.idx_off] : 0;
    const float* src = t.src + (size_t)idx * t.R * t.C;
    int tpr = t.C >> 5;
    int tr = bid / tpr, tc = bid % tpr;
    __shared__ u16 tile[32][33];
    int tx = threadIdx.x & 31, ty = threadIdx.x >> 5;  // 32 x 8
#pragma unroll
    for (int r = ty; r < 32; r += 8)
        tile[r][tx] = f2u(src[(size_t)(tr * 32 + r) * t.C + tc * 32 + tx]);
    __syncthreads();
#pragma unroll
    for (int r = ty; r < 32; r += 8)
        t.dst[(size_t)(tc * 32 + r) * t.R + tr * 32 + tx] = tile[tx][r];
}

// f32 -> bf16, two tensors (blockIdx.y picks tensor), 8 elems/thread
__global__ __launch_bounds__(256)
void f2b_kernel(const float* __restrict__ xa, const float* __restrict__ xb,
                u16* __restrict__ oa, u16* __restrict__ ob)
{
    int i = (blockIdx.x * 256 + threadIdx.x) * 8;
    const float* src = blockIdx.y ? xb : xa;
    u16* dst = blockIdx.y ? ob : oa;
    float4 f0 = *(const float4*)(src + i);
    float4 f1 = *(const float4*)(src + i + 4);
    float vv[8] = {f0.x, f0.y, f0.z, f0.w, f1.x, f1.y, f1.z, f1.w};
    __align__(16) u16 o8[8];
#pragma unroll
    for (int t = 0; t < 8; t++) o8[t] = f2u(vv[t]);
    *(uint4*)(dst + i) = *(const uint4*)o8;
}

extern "C" void kernel_launch(void* const* d_in, const int* in_sizes, int n_in,
                              void* d_out, int out_size, void* d_ws, size_t ws_size,
                              hipStream_t stream)
{
    const float* in_c   = (const float*)d_in[0];
    const float* in_b   = (const float*)d_in[1];
    const float* torsion= (const float*)d_in[2];
    const float* wsel_c = (const float*)d_in[3];
    const float* bsel_c = (const float*)d_in[4];
    const float* wsel_b = (const float*)d_in[5];
    const float* bsel_b = (const float*)d_in[6];
    const float* c_ln_g = (const float*)d_in[7];
    const float* c_ln_b = (const float*)d_in[8];
    const float* c_w1   = (const float*)d_in[9];
    const float* c_b1   = (const float*)d_in[10];
    const float* c_w2   = (const float*)d_in[11];
    const float* c_b2   = (const float*)d_in[12];
    const float* c_gate = (const float*)d_in[13];
    const float* b_ln_g = (const float*)d_in[14];
    const float* b_ln_b = (const float*)d_in[15];
    const float* b_w1   = (const float*)d_in[16];
    const float* b_b1   = (const float*)d_in[17];
    const float* b_w2   = (const float*)d_in[18];
    const float* b_b2   = (const float*)d_in[19];
    const float* b_gate = (const float*)d_in[20];
    const float* w_cross= (const float*)d_in[21];
    const float* b_cross= (const float*)d_in[22];

    const size_t SD = (size_t)8192 * 512;  // elements per [B,S,D] tensor

    // fp32 state lives directly in d_out (no final copies)
    float* x_c  = (float*)d_out;
    float* x_b  = x_c + SD;
    float* out_f = x_b + SD;

    char* w = (char*)d_ws;
    u16* lnc   = (u16*)w; w += SD * 2;                 // 8.4 MB
    u16* lnb   = (u16*)w; w += SD * 2;                 // 8.4 MB
    u16* act_c = (u16*)w; w += SD * 2 * 2;             // 16.8 MB (N=1024)
    u16* act_b = (u16*)w; w += SD * 2;                 // 8.4 MB
    u16* cbf   = (u16*)w; w += SD * 2;                 // 8.4 MB
    u16* bbf   = (u16*)w; w += SD * 2;                 // 8.4 MB
    float* mean_c = (float*)w; w += (size_t)16 * 512 * 4;
    float* mean_b = (float*)w; w += (size_t)16 * 512 * 4;
    int*   idxbuf = (int*)w;   w += 256;
    u16* w1t_c = (u16*)w; w += (size_t)1024 * 512 * 2; // [1024][512]
    u16* w2t_c = (u16*)w; w += (size_t)1024 * 512 * 2; // [512][1024]
    u16* w1t_b = (u16*)w; w += (size_t)512 * 512 * 2;  // [512][512]
    u16* w2t_b = (u16*)w; w += (size_t)512 * 512 * 2;
    u16* wxT   = (u16*)w; w += (size_t)1024 * 512 * 2; // [512][1024]

    // inputs -> fp32 working state (in d_out)
    hipMemcpyAsync(x_c, in_c, SD * 4, hipMemcpyDeviceToDevice, stream);
    hipMemcpyAsync(x_b, in_b, SD * 4, hipMemcpyDeviceToDevice, stream);

    // w_cross[3]^T once
    TArg twx = { w_cross + (size_t)3 * 1024 * 512, wxT, 1024, 512, -1, 512 };
    TArg tz  = { nullptr, nullptr, 32, 32, -1, 0 };
    transpose4<<<512, 256, 0, stream>>>(twx, tz, tz, tz, idxbuf);

    for (int l = 0; l < 4; l++) {
        zero_kernel<<<64, 256, 0, stream>>>(mean_c, 16384);  // mean_c+mean_b contiguous
        mean_kernel<<<256, 512, 0, stream>>>(x_c, x_b, mean_c, mean_b);
        route_kernel<<<1, 128, 0, stream>>>(mean_c, mean_b,
            wsel_c + (size_t)l * 512 * 8, bsel_c + (size_t)l * 8,
            wsel_b + (size_t)l * 512 * 8, bsel_b + (size_t)l * 8, idxbuf);

        for (int j = 0; j < 2; j++) {
            // transpose the 4 selected weight matrices
            TArg tc1 = { c_w1 + (size_t)l * NB_ * 512 * 1024, w1t_c, 512, 1024, j, 512 };
            TArg tc2 = { c_w2 + (size_t)l * NB_ * 1024 * 512, w2t_c, 1024, 512, j, 512 };
            TArg tb1 = { b_w1 + (size_t)l * NB_ * 512 * 512,  w1t_b, 512, 512, 2 + j, 256 };
            TArg tb2 = { b_w2 + (size_t)l * NB_ * 512 * 512,  w2t_b, 512, 512, 2 + j, 256 };
            transpose4<<<1536, 256, 0, stream>>>(tc1, tc2, tb1, tb2, idxbuf);

            // LN both pathways
            ln_dual<<<16384, 64, 0, stream>>>(x_c, x_b, lnc, lnb,
                c_ln_g + (size_t)l * NB_ * 512, c_ln_b + (size_t)l * NB_ * 512,
                b_ln_g + (size_t)l * NB_ * 512, b_ln_b + (size_t)l * NB_ * 512,
                idxbuf, j);

            // GEMM1: c (N=1024, gelu) + b (N=512, tanh)
            GArg g1c = { lnc, nullptr, 512, 1 << 30, w1t_c,
                         c_b1 + (size_t)l * NB_ * 1024, 1024,
                         nullptr, 0, nullptr, act_c, nullptr, 1024, 512, j, 0 };
            GArg g1b = { lnb, nullptr, 512, 1 << 30, w1t_b,
                         b_b1 + (size_t)l * NB_ * 512, 512,
                         nullptr, 0, nullptr, act_b, nullptr, 512, 512, 2 + j, 1 };
            gemm_dual<<<dim3(64, 12), 256, 0, stream>>>(g1c, g1b, 8, idxbuf, torsion);

            // GEMM2: c (K=1024) + b (K=512), residual epilogue into x (fp32)
            GArg g2c = { act_c, nullptr, 1024, 1 << 30, w2t_c,
                         c_b2 + (size_t)l * NB_ * 512, 512,
                         c_gate + (size_t)l * NB_ * 512, 512, mean_b,
                         nullptr, x_c, 512, 1024, j, 2 };
            GArg g2b = { act_b, nullptr, 512, 1 << 30, w2t_b,
                         b_b2 + (size_t)l * NB_ * 512, 512,
                         b_gate + (size_t)l * NB_ * 512, 512, mean_c,
                         nullptr, x_b, 512, 512, 2 + j, 2 };
            gemm_dual<<<dim3(64, 8), 256, 0, stream>>>(g2c, g2b, 4, idxbuf, torsion);
        }
    }

    // bf16 copies of final c/b for the fused GEMM's A operand
    f2b_kernel<<<dim3(2048, 2), 256, 0, stream>>>(x_c, x_b, cbf, bbf);
    // fused = concat([c,b]) @ w_cross[3] + b_cross[3]  (fp32 out)
    GArg gf = { cbf, bbf, 512, 512, wxT,
                b_cross + (size_t)3 * 512, 0,
                nullptr, 0, nullptr, nullptr, out_f, 512, 1024, -1, 3 };
    gemm_dual<<<dim3(64, 4), 256, 0, stream>>>(gf, gf, 4, idxbuf, torsion);
}